// Round 4
// baseline (401.435 us; speedup 1.0000x reference)
//
#include <hip/hip_runtime.h>
#include <math.h>

#define D_MODEL 512
#define BATCH 8
#define SEQ 512
#define HEAD 64
#define DK 4
#define DV 8
#define HIDD 10

// ---------------------------------------------------------------------------
// 64x64-tile transpose: x[4096][512] -> xT[512][4096], ditto x_enc.
// ---------------------------------------------------------------------------
__global__ __launch_bounds__(256) void transpose_kernel(
    const float* __restrict__ x, const float* __restrict__ xe,
    float* __restrict__ xT, float* __restrict__ xeT)
{
    __shared__ float tile[64][65];
    int bid = blockIdx.x;
    const float* src; float* dst;
    if (bid < 512) { src = x;  dst = xT; }
    else           { src = xe; dst = xeT; bid -= 512; }
    const int R0 = (bid >> 3) * 64;     // 64 row-tiles
    const int C0 = (bid & 7) * 64;      // 8 col-tiles
    const int t = threadIdx.x;
    const int rr = t >> 4, c4 = (t & 15) * 4;
#pragma unroll
    for (int i = 0; i < 4; ++i) {
        const float4 v = *(const float4*)(src + (long)(R0 + i * 16 + rr) * 512 + C0 + c4);
        tile[i * 16 + rr][c4 + 0] = v.x; tile[i * 16 + rr][c4 + 1] = v.y;
        tile[i * 16 + rr][c4 + 2] = v.z; tile[i * 16 + rr][c4 + 3] = v.w;
    }
    __syncthreads();
#pragma unroll
    for (int i = 0; i < 4; ++i) {
        const int oc = i * 16 + rr;     // original column = output row
        float4 v;
        v.x = tile[c4 + 0][oc]; v.y = tile[c4 + 1][oc];
        v.z = tile[c4 + 2][oc]; v.w = tile[c4 + 3][oc];
        *(float4*)(dst + (long)(C0 + oc) * 4096 + R0 + c4) = v;
    }
}

// ---------------------------------------------------------------------------
// proj1: zero-LDS GEMM, plain C. Lane = output row -> x operand is ONE
// coalesced dword per k; the 32-col W slice address depends only on
// blockIdx + loop k -> wave-uniform -> hipcc's uniformity analysis emits
// s_load (scalar pipe). No LDS, no barriers; 32 v_fmac per k per lane.
// Worst case (no scalarization): all-lane-uniform dwordx4 loads = 1 cache
// line each, W is L2-resident (2 MB < 4 MB/XCD) -> still ~VALU-bound.
// grid (56 col-jobs, 32 row-blocks of 128) = 1792 blocks = 14 waves/CU.
// ---------------------------------------------------------------------------
__global__ __launch_bounds__(128) void proj_kernel(
    const float* __restrict__ xT, const float* __restrict__ xeT,
    const float* __restrict__ Wq, const float* __restrict__ Wk,
    const float* __restrict__ Wv,
    float* __restrict__ Q1, float* __restrict__ K1, float* __restrict__ V1,
    float* __restrict__ Kc, float* __restrict__ Vc)
{
    const int cj = blockIdx.x;                    // 0..55 col-job (uniform)
    const float* Xt; const float* W; int ldw; int c0; float* dst; int vt;
    if (cj < 8)       { Xt = xT;  W = Wq; ldw = 256; c0 = cj * 32;        dst = Q1; vt = 0; }
    else if (cj < 16) { Xt = xT;  W = Wk; ldw = 256; c0 = (cj - 8) * 32;  dst = K1; vt = 0; }
    else if (cj < 32) { Xt = xT;  W = Wv; ldw = 512; c0 = (cj - 16) * 32; dst = V1; vt = 1; }
    else if (cj < 40) { Xt = xeT; W = Wk; ldw = 256; c0 = (cj - 32) * 32; dst = Kc; vt = 0; }
    else              { Xt = xeT; W = Wv; ldw = 512; c0 = (cj - 40) * 32; dst = Vc; vt = 1; }

    const int row = blockIdx.y * 128 + threadIdx.x;   // 0..4095 (per lane)
    const float* xp = Xt + row;
    const float* wp = W + c0;

    float acc[32];
#pragma unroll
    for (int j = 0; j < 32; ++j) acc[j] = 0.f;

#pragma unroll 4
    for (int k = 0; k < 512; ++k) {
        const float xv = xp[(long)k * 4096];          // coalesced, per-lane
        const float* wr = wp + (long)k * ldw;         // wave-uniform address
#pragma unroll
        for (int j = 0; j < 8; ++j) {
            const float4 w4 = *(const float4*)(wr + j * 4);
            acc[j * 4 + 0] = fmaf(xv, w4.x, acc[j * 4 + 0]);
            acc[j * 4 + 1] = fmaf(xv, w4.y, acc[j * 4 + 1]);
            acc[j * 4 + 2] = fmaf(xv, w4.z, acc[j * 4 + 2]);
            acc[j * 4 + 3] = fmaf(xv, w4.w, acc[j * 4 + 3]);
        }
    }

    const int b = row >> 9, s = row & 511;
    if (vt == 0) {
        const int hb = c0 >> 2;       // 8 heads x 4 dims
#pragma unroll
        for (int j = 0; j < 8; ++j)
            *(float4*)(dst + (((long)b * HEAD + hb + j) * SEQ + s) * 4) =
                *(const float4*)(acc + 4 * j);
    } else {
        const int hb = c0 >> 3;       // 4 heads x 8 dims
#pragma unroll
        for (int j = 0; j < 4; ++j) {
            const long base = (((long)b * HEAD + hb + j) * SEQ + s) * 8;
            *(float4*)(dst + base)     = *(const float4*)(acc + 8 * j);
            *(float4*)(dst + base + 4) = *(const float4*)(acc + 8 * j + 4);
        }
    }
}

// ---------------------------------------------------------------------------
// proj2: Q only (attn1 output consumed solely as stage-2 Q). Same zero-LDS
// structure on transposed input AT. Split-K x2 (kh=0 -> Qa, kh=1 -> Qb;
// attn sums on load). grid (16,32,2) = 1024 blocks = 8 waves/CU.
// ---------------------------------------------------------------------------
__global__ __launch_bounds__(128) void proj2_kernel(
    const float* __restrict__ AT, const float* __restrict__ Wq,
    float* __restrict__ Qa, float* __restrict__ Qb)
{
    const int c0 = blockIdx.x * 16;
    const int row = blockIdx.y * 128 + threadIdx.x;
    const int kb = blockIdx.z * 256;
    float* dst = blockIdx.z ? Qb : Qa;
    const float* xp = AT + row;
    const float* wp = Wq + c0;

    float acc[16];
#pragma unroll
    for (int j = 0; j < 16; ++j) acc[j] = 0.f;

#pragma unroll 4
    for (int k = kb; k < kb + 256; ++k) {
        const float xv = xp[(long)k * 4096];
        const float* wr = wp + (long)k * 256;
#pragma unroll
        for (int j = 0; j < 4; ++j) {
            const float4 w4 = *(const float4*)(wr + j * 4);
            acc[j * 4 + 0] = fmaf(xv, w4.x, acc[j * 4 + 0]);
            acc[j * 4 + 1] = fmaf(xv, w4.y, acc[j * 4 + 1]);
            acc[j * 4 + 2] = fmaf(xv, w4.z, acc[j * 4 + 2]);
            acc[j * 4 + 3] = fmaf(xv, w4.w, acc[j * 4 + 3]);
        }
    }

    const int b = row >> 9, s = row & 511;
    const int hb = c0 >> 2;           // 4 heads x 4 dims
#pragma unroll
    for (int j = 0; j < 4; ++j)
        *(float4*)(dst + (((long)b * HEAD + hb + j) * SEQ + s) * 4) =
            *(const float4*)(acc + 4 * j);
}

// ---------------------------------------------------------------------------
// Attention, split-K x2, no LDS (r2-proven): all lanes of a wave visit the
// same key, so K/V loads are wave-uniform -> scalarized by the compiler.
// Scores in log2 domain; masked scores EXACTLY 0 and participate
// (multiplicative-tril quirk). Writes unnormalized partials.
// ---------------------------------------------------------------------------
template <int MASKED>
__device__ __forceinline__ void attn_scan(
    const float* __restrict__ Kp, const float* __restrict__ Vp, const int qb,
    const float q0, const float q1, const float q2, const float q3,
    float& m, float& l, float (&a)[8])
{
    for (int s0 = 0; s0 < 256; s0 += 8) {
        float sc[8];
#pragma unroll
        for (int i = 0; i < 8; ++i) {
            const float4 k4 = *(const float4*)(Kp + (s0 + i) * DK);
            const float d = fmaf(q0, k4.x, fmaf(q1, k4.y, fmaf(q2, k4.z, q3 * k4.w)));
            sc[i] = (MASKED && (s0 + i) > qb) ? 0.f : d;
        }
        const float gm = fmaxf(fmaxf(fmaxf(sc[0], sc[1]), fmaxf(sc[2], sc[3])),
                               fmaxf(fmaxf(sc[4], sc[5]), fmaxf(sc[6], sc[7])));
        if (gm > m) {
            const float scale = __builtin_amdgcn_exp2f(m - gm);  // exp2(-inf)=0
            l *= scale;
#pragma unroll
            for (int r = 0; r < 8; ++r) a[r] *= scale;
            m = gm;
        }
#pragma unroll
        for (int i = 0; i < 8; ++i) {
            const float p = __builtin_amdgcn_exp2f(sc[i] - m);
            l += p;
            const float4 v0 = *(const float4*)(Vp + (s0 + i) * DV);
            const float4 v1 = *(const float4*)(Vp + (s0 + i) * DV + 4);
            a[0] = fmaf(p, v0.x, a[0]); a[1] = fmaf(p, v0.y, a[1]);
            a[2] = fmaf(p, v0.z, a[2]); a[3] = fmaf(p, v0.w, a[3]);
            a[4] = fmaf(p, v1.x, a[4]); a[5] = fmaf(p, v1.y, a[5]);
            a[6] = fmaf(p, v1.z, a[6]); a[7] = fmaf(p, v1.w, a[7]);
        }
    }
}

__global__ __launch_bounds__(256) void attn_kernel(
    const float* __restrict__ Qa, const float* __restrict__ Qb,
    const float* __restrict__ K2, const float* __restrict__ V2,
    float* __restrict__ PA, float* __restrict__ PM, const int causal)
{
    const int t  = threadIdx.x;
    const int bh = blockIdx.x >> 2;
    const int qh = (blockIdx.x >> 1) & 1;
    const int kh = blockIdx.x & 1;
    const int q  = qh * 256 + t;

    const float* Kp = K2 + ((long)bh * SEQ + kh * 256) * DK;
    const float* Vp = V2 + ((long)bh * SEQ + kh * 256) * DV;

    float m, l, a[8];

    if (causal && kh == 1 && qh == 0) {
        // Fully masked quadrant: all scores exactly 0 -> (m=0, l=256,
        // a = column-sum of V). Lanes split the sum, butterfly-reduce.
        const int lane = t & 63;
        float s[8] = {0.f, 0.f, 0.f, 0.f, 0.f, 0.f, 0.f, 0.f};
#pragma unroll
        for (int i = 0; i < 4; ++i) {
            const float4 v0 = *(const float4*)(Vp + (lane + i * 64) * DV);
            const float4 v1 = *(const float4*)(Vp + (lane + i * 64) * DV + 4);
            s[0] += v0.x; s[1] += v0.y; s[2] += v0.z; s[3] += v0.w;
            s[4] += v1.x; s[5] += v1.y; s[6] += v1.z; s[7] += v1.w;
        }
#pragma unroll
        for (int o = 32; o > 0; o >>= 1)
#pragma unroll
            for (int j = 0; j < 8; ++j) s[j] += __shfl_xor(s[j], o);
        m = 0.f; l = 256.f;
#pragma unroll
        for (int j = 0; j < 8; ++j) a[j] = s[j];
    } else {
        float4 qv = *(const float4*)(Qa + ((long)bh * SEQ + q) * DK);
        if (Qb) {                        // split-K projected Q: sum halves
            const float4 qw = *(const float4*)(Qb + ((long)bh * SEQ + q) * DK);
            qv.x += qw.x; qv.y += qw.y; qv.z += qw.z; qv.w += qw.w;
        }
        const float cf = 0.5f * 1.44269504088896340736f;  // 1/sqrt(DK)*log2e
        const float q0 = qv.x * cf, q1 = qv.y * cf;
        const float q2 = qv.z * cf, q3 = qv.w * cf;

        m = -INFINITY; l = 0.f;
#pragma unroll
        for (int r = 0; r < 8; ++r) a[r] = 0.f;

        if (!causal || (kh == 0 && qh == 1))   // no key of this half masked
            attn_scan<0>(Kp, Vp, 255, q0, q1, q2, q3, m, l, a);
        else                                   // boundary inside this half
            attn_scan<1>(Kp, Vp, q - kh * 256, q0, q1, q2, q3, m, l, a);
    }

    const long p = ((long)(bh * 2 + kh)) * SEQ + q;
    *(float4*)(PA + p * 8)     = make_float4(a[0], a[1], a[2], a[3]);
    *(float4*)(PA + p * 8 + 4) = make_float4(a[4], a[5], a[6], a[7]);
    *(float2*)(PM + p * 2)     = make_float2(m, l);
}

// ---------------------------------------------------------------------------
// Combine the two K-half partials of stage 1 -> AT[512][4096] (TRANSPOSED:
// row = model-dim, col = b*512+q) so proj2 reads it like xT. Stores are
// 8 coalesced dword streams (consecutive tid = consecutive q).
// ---------------------------------------------------------------------------
__global__ __launch_bounds__(256) void combine_kernel(
    const float* __restrict__ PA, const float* __restrict__ PM,
    float* __restrict__ AT)
{
    const int tid = blockIdx.x * 256 + threadIdx.x;   // 0..262143
    const int bh  = tid >> 9;
    const int q   = tid & 511;
    const long p0 = ((long)bh * 2 + 0) * SEQ + q;
    const long p1 = ((long)bh * 2 + 1) * SEQ + q;
    const float2 ml0 = *(const float2*)(PM + p0 * 2);
    const float2 ml1 = *(const float2*)(PM + p1 * 2);
    const float M = fmaxf(ml0.x, ml1.x);
    float w0 = __builtin_amdgcn_exp2f(ml0.x - M);
    float w1 = __builtin_amdgcn_exp2f(ml1.x - M);
    const float inv = 1.0f / fmaf(ml0.y, w0, ml1.y * w1);
    w0 *= inv; w1 *= inv;
    const float4 x0 = *(const float4*)(PA + p0 * 8);
    const float4 x1 = *(const float4*)(PA + p0 * 8 + 4);
    const float4 y0 = *(const float4*)(PA + p1 * 8);
    const float4 y1 = *(const float4*)(PA + p1 * 8 + 4);
    const float o[8] = {
        x0.x * w0 + y0.x * w1, x0.y * w0 + y0.y * w1,
        x0.z * w0 + y0.z * w1, x0.w * w0 + y0.w * w1,
        x1.x * w0 + y1.x * w1, x1.y * w0 + y1.y * w1,
        x1.z * w0 + y1.z * w1, x1.w * w0 + y1.w * w1};
    const int b = bh >> 6, h = bh & 63;
    const int r = b * 512 + q;          // global row (matches xT convention)
#pragma unroll
    for (int j = 0; j < 8; ++j)
        AT[(long)(h * 8 + j) * 4096 + r] = o[j];
}

// ---------------------------------------------------------------------------
// Fused stage-2 combine + residual + LayerNorm + MLP (512 -> 10 -> 512).
// One WAVE per row; lane == head (e0 = lane*8 spans exactly head `lane`).
// ---------------------------------------------------------------------------
__global__ __launch_bounds__(256) void ln_mlp_kernel(
    const float* __restrict__ x,
    const float* __restrict__ PA, const float* __restrict__ PM,
    const float* __restrict__ g, const float* __restrict__ beta,
    const float* __restrict__ w1, const float* __restrict__ b1,
    const float* __restrict__ w2, const float* __restrict__ b2,
    float* __restrict__ out)
{
    const int t = threadIdx.x;
    const int lane = t & 63;
    const int row = blockIdx.x * 4 + (t >> 6);
    const int b = row >> 9, q = row & 511;
    const long base = (long)row * D_MODEL;
    const int e0 = lane * 8;

    const long p0 = (((long)b * HEAD + lane) * 2 + 0) * SEQ + q;
    const long p1 = (((long)b * HEAD + lane) * 2 + 1) * SEQ + q;
    const float2 ml0 = *(const float2*)(PM + p0 * 2);
    const float2 ml1 = *(const float2*)(PM + p1 * 2);
    const float M = fmaxf(ml0.x, ml1.x);
    float cw0 = __builtin_amdgcn_exp2f(ml0.x - M);
    float cw1 = __builtin_amdgcn_exp2f(ml1.x - M);
    const float inv = 1.0f / fmaf(ml0.y, cw0, ml1.y * cw1);
    cw0 *= inv; cw1 *= inv;
    const float4 fa0 = *(const float4*)(PA + p0 * 8);
    const float4 fa1 = *(const float4*)(PA + p0 * 8 + 4);
    const float4 fb0 = *(const float4*)(PA + p1 * 8);
    const float4 fb1 = *(const float4*)(PA + p1 * 8 + 4);

    const float4 xa = *(const float4*)(x + base + e0);
    const float4 xb = *(const float4*)(x + base + e0 + 4);
    float z[8] = {
        xa.x + fa0.x * cw0 + fb0.x * cw1, xa.y + fa0.y * cw0 + fb0.y * cw1,
        xa.z + fa0.z * cw0 + fb0.z * cw1, xa.w + fa0.w * cw0 + fb0.w * cw1,
        xb.x + fa1.x * cw0 + fb1.x * cw1, xb.y + fa1.y * cw0 + fb1.y * cw1,
        xb.z + fa1.z * cw0 + fb1.z * cw1, xb.w + fa1.w * cw0 + fb1.w * cw1};

    float sum = 0.f;
#pragma unroll
    for (int j = 0; j < 8; ++j) sum += z[j];
#pragma unroll
    for (int o = 32; o > 0; o >>= 1) sum += __shfl_xor(sum, o);
    const float mu = sum * (1.0f / 512.0f);

    float d[8], ss = 0.f;
#pragma unroll
    for (int j = 0; j < 8; ++j) { d[j] = z[j] - mu; ss += d[j] * d[j]; }
#pragma unroll
    for (int o = 32; o > 0; o >>= 1) ss += __shfl_xor(ss, o);
    const float rs = rsqrtf(ss * (1.0f / 512.0f) + 1e-5f);

    const float4 ga = *(const float4*)(g + e0);
    const float4 gb = *(const float4*)(g + e0 + 4);
    const float4 ba = *(const float4*)(beta + e0);
    const float4 bb = *(const float4*)(beta + e0 + 4);
    const float gg[8] = {ga.x, ga.y, ga.z, ga.w, gb.x, gb.y, gb.z, gb.w};
    const float bt[8] = {ba.x, ba.y, ba.z, ba.w, bb.x, bb.y, bb.z, bb.w};
    float y[8];
#pragma unroll
    for (int j = 0; j < 8; ++j) y[j] = d[j] * rs * gg[j] + bt[j];

    float part[HIDD];
#pragma unroll
    for (int i = 0; i < HIDD; ++i) {
        const float4 wa = *(const float4*)(w1 + i * 512 + e0);
        const float4 wb = *(const float4*)(w1 + i * 512 + e0 + 4);
        part[i] = y[0] * wa.x + y[1] * wa.y + y[2] * wa.z + y[3] * wa.w
                + y[4] * wb.x + y[5] * wb.y + y[6] * wb.z + y[7] * wb.w;
    }
#pragma unroll
    for (int i = 0; i < HIDD; ++i)
#pragma unroll
        for (int o = 32; o > 0; o >>= 1) part[i] += __shfl_xor(part[i], o);

    float hv[HIDD];
#pragma unroll
    for (int i = 0; i < HIDD; ++i) hv[i] = fmaxf(part[i] + b1[i], 0.f);

    const float4 b2a = *(const float4*)(b2 + e0);
    const float4 b2b = *(const float4*)(b2 + e0 + 4);
    float o8[8] = {b2a.x, b2a.y, b2a.z, b2a.w, b2b.x, b2b.y, b2b.z, b2b.w};
#pragma unroll
    for (int j = 0; j < 8; ++j) {
        const float* wr = w2 + (long)(e0 + j) * 10;
        const float2 wA = *(const float2*)(wr);
        const float2 wB = *(const float2*)(wr + 2);
        const float2 wC = *(const float2*)(wr + 4);
        const float2 wD = *(const float2*)(wr + 6);
        const float2 wE = *(const float2*)(wr + 8);
        o8[j] += hv[0] * wA.x + hv[1] * wA.y + hv[2] * wB.x + hv[3] * wB.y
               + hv[4] * wC.x + hv[5] * wC.y + hv[6] * wD.x + hv[7] * wD.y
               + hv[8] * wE.x + hv[9] * wE.y;
    }

    *(float4*)(out + base + e0)     = make_float4(o8[0], o8[1], o8[2], o8[3]);
    *(float4*)(out + base + e0 + 4) = make_float4(o8[4], o8[5], o8[6], o8[7]);
}

extern "C" void kernel_launch(void* const* d_in, const int* in_sizes, int n_in,
                              void* d_out, int out_size, void* d_ws, size_t ws_size,
                              hipStream_t stream) {
    (void)in_sizes; (void)n_in; (void)out_size; (void)ws_size;
    const float* x    = (const float*)d_in[0];
    const float* xenc = (const float*)d_in[1];
    const float* Wq   = (const float*)d_in[2];
    const float* Wk   = (const float*)d_in[3];
    const float* Wv   = (const float*)d_in[4];
    const float* ln_g = (const float*)d_in[5];
    const float* ln_b = (const float*)d_in[6];
    const float* w1   = (const float*)d_in[7];
    const float* b1   = (const float*)d_in[8];
    const float* w2   = (const float*)d_in[9];
    const float* b2   = (const float*)d_in[10];
    float* out = (float*)d_out;

    // Workspace: EXACTLY 12M floats = 48 MiB (the size every passing round
    // used; r3's 60 MiB growth is a prime crash suspect). Aliasing with
    // verified liveness:
    //   step            reads                   writes
    //   transpose       x,xe                    xT[0,2M) xeT[2,4M)
    //   proj1           xT,xeT                  Q1[4,5) K1[5,6) V1[6,8) Kc[8,9) Vc[9,11)
    //   attn1           Q1,K1,V1                PA[0,4)  (xT/xeT dead)  PM[11,12)
    //   combine         PA,PM                   AT[4,6)  (Q1,K1 dead)
    //   proj2           AT                      Qa[6,7) Qb[7,8)  (V1 dead)
    //   attn2           Qa,Qb,Kc,Vc             PA[0,4) PM[11,12)  (PA1/PM1 dead)
    //   ln_mlp          x,PA,PM                 out
    float* ws  = (float*)d_ws;
    float* xT  = ws;                   // [0,2M)
    float* xeT = ws + 2097152;         // [2M,4M)
    float* Q1  = ws + 4194304;         // [4M,5M)
    float* K1  = ws + 5242880;         // [5M,6M)
    float* V1  = ws + 6291456;         // [6M,8M)
    float* Kc  = ws + 8388608;         // [8M,9M)
    float* Vc  = ws + 9437184;         // [9M,11M)
    float* PA  = ws;                   // [0,4M)   both stages
    float* PM  = ws + 11534336;        // [11M,12M) both stages
    float* AT  = ws + 4194304;         // [4M,6M)
    float* Qa  = ws + 6291456;         // [6M,7M)
    float* Qb  = ws + 7340032;         // [7M,8M)

    transpose_kernel<<<dim3(1024), 256, 0, stream>>>(x, xenc, xT, xeT);
    proj_kernel<<<dim3(56, 32), 128, 0, stream>>>(xT, xeT, Wq, Wk, Wv,
                                                  Q1, K1, V1, Kc, Vc);
    attn_kernel<<<dim3(2048), 256, 0, stream>>>(Q1, nullptr, K1, V1, PA, PM, 1);
    combine_kernel<<<dim3(1024), 256, 0, stream>>>(PA, PM, AT);
    proj2_kernel<<<dim3(16, 32, 2), 128, 0, stream>>>(AT, Wq, Qa, Qb);
    attn_kernel<<<dim3(2048), 256, 0, stream>>>(Qa, Qb, Kc, Vc, PA, PM, 0);
    ln_mlp_kernel<<<dim3(1024), 256, 0, stream>>>(x, PA, PM, ln_g, ln_b,
                                                  w1, b1, w2, b2, out);
}

// Round 5
// 343.271 us; speedup vs baseline: 1.1694x; 1.1694x over previous
//
#include <hip/hip_runtime.h>
#include <math.h>

#define D_MODEL 512
#define BATCH 8
#define SEQ 512
#define HEAD 64
#define DK 4
#define DV 8
#define HIDD 10

// proj tiled-GEMM params (r0-proven: best measured fp32 GEMM structure)
#define MR 32    // rows per block
#define KC 32    // k-chunk
#define NC 256   // cols per block (36 KB LDS -> 4 blocks/CU)

__device__ __forceinline__ float4 fma4(float s, float4 w, float4 a) {
    a.x = fmaf(s, w.x, a.x); a.y = fmaf(s, w.y, a.y);
    a.z = fmaf(s, w.z, a.z); a.w = fmaf(s, w.w, a.w);
    return a;
}

// ---------------------------------------------------------------------------
// proj: r0's proven kernel, extended from 4 to 7 col-jobs so the cross-stage
// K/V (x_enc-only inputs) ride the same launch: 896 blocks = 3.5 blocks/CU
// (vs r0's 2/CU, which left VALUBusy at 41%). Structure otherwise identical.
// Outputs head-major: Q/K = [b][h][s][4], V = [b][h][s][8].
// ---------------------------------------------------------------------------
__global__ __launch_bounds__(256) void proj_kernel(
    const float* __restrict__ x, const float* __restrict__ xe,
    const float* __restrict__ Wq, const float* __restrict__ Wk,
    const float* __restrict__ Wv,
    float* __restrict__ Q2, float* __restrict__ K2, float* __restrict__ V2,
    float* __restrict__ Kc, float* __restrict__ Vc)
{
    __shared__ float xt[KC * MR];   // [k][r]  4 KB
    __shared__ float wt[KC * NC];   // [k][c] 32 KB

    const int t  = threadIdx.x;
    const int bj = blockIdx.x >> 7;      // 0..6 col-job
    const int br = blockIdx.x & 127;     // row block
    const int r0 = br * MR;

    const float* X; const float* W; int ldw; int c0; float* dst; int vt;
    switch (bj) {
      case 0:  X = x;  W = Wq; ldw = 256; c0 = 0;   dst = Q2; vt = 0; break;
      case 1:  X = x;  W = Wk; ldw = 256; c0 = 0;   dst = K2; vt = 0; break;
      case 2:  X = x;  W = Wv; ldw = 512; c0 = 0;   dst = V2; vt = 1; break;
      case 3:  X = x;  W = Wv; ldw = 512; c0 = 256; dst = V2; vt = 1; break;
      case 4:  X = xe; W = Wk; ldw = 256; c0 = 0;   dst = Kc; vt = 0; break;
      case 5:  X = xe; W = Wv; ldw = 512; c0 = 0;   dst = Vc; vt = 1; break;
      default: X = xe; W = Wv; ldw = 512; c0 = 256; dst = Vc; vt = 1; break;
    }

    const int rg = t >> 6;          // wave id -> rows rg*8..rg*8+7
    const int cq = t & 63;          // cols cq*4..cq*4+3
    const int rs = t & 31;          // x-staging: row
    const int kq = t >> 5;          // x-staging: k-quad 0..7

    float4 acc[8];
#pragma unroll
    for (int r = 0; r < 8; ++r) acc[r] = make_float4(0.f, 0.f, 0.f, 0.f);

    for (int kc = 0; kc < D_MODEL; kc += KC) {
        // ---- stage x tile (transposed [k][r]; 2-way bank groups = free) ----
        const float4 xa = *(const float4*)(X + (long)(r0 + rs) * D_MODEL + kc + kq * 4);
        xt[(kq * 4 + 0) * MR + rs] = xa.x;
        xt[(kq * 4 + 1) * MR + rs] = xa.y;
        xt[(kq * 4 + 2) * MR + rs] = xa.z;
        xt[(kq * 4 + 3) * MR + rs] = xa.w;

        // ---- stage W tile: wave rg loads rows i*4+rg, 1 KB contiguous ----
#pragma unroll
        for (int i = 0; i < 8; ++i) {
            const int row = i * 4 + rg;
            *(float4*)(wt + row * NC + cq * 4) =
                *(const float4*)(W + (long)(kc + row) * ldw + c0 + cq * 4);
        }
        __syncthreads();

        // ---- compute: 8x4 register block, 32 FMA per k ----
#pragma unroll 4
        for (int k = 0; k < KC; ++k) {
            const float4 w4 = *(const float4*)(wt + k * NC + cq * 4);
            const float4 x0 = *(const float4*)(xt + k * MR + rg * 8);
            const float4 x1 = *(const float4*)(xt + k * MR + rg * 8 + 4);
            acc[0] = fma4(x0.x, w4, acc[0]);
            acc[1] = fma4(x0.y, w4, acc[1]);
            acc[2] = fma4(x0.z, w4, acc[2]);
            acc[3] = fma4(x0.w, w4, acc[3]);
            acc[4] = fma4(x1.x, w4, acc[4]);
            acc[5] = fma4(x1.y, w4, acc[5]);
            acc[6] = fma4(x1.z, w4, acc[6]);
            acc[7] = fma4(x1.w, w4, acc[7]);
        }
        __syncthreads();
    }

    // ---- epilogue: head-major scatter (L2 merges adjacent s-rows) ----
    const int b = r0 >> 9;              // all 32 rows of a block share b
    const int sb = (r0 & 511) + rg * 8;
    if (vt == 0) {
#pragma unroll
        for (int r = 0; r < 8; ++r)
            *(float4*)(dst + (((long)b * HEAD + cq) * SEQ + sb + r) * 4) = acc[r];
    } else {
        const int col = c0 + cq * 4;
        const int h = col >> 3;
        const int off = col & 7;        // 0 or 4
#pragma unroll
        for (int r = 0; r < 8; ++r)
            *(float4*)(dst + (((long)b * HEAD + h) * SEQ + sb + r) * 8 + off) = acc[r];
    }
}

// ---------------------------------------------------------------------------
// proj2 (r1-proven): Q only — attn1's output A is consumed solely as the
// stage-2 query. Split-K x2 (kh=0 -> Qa, kh=1 -> Qb; attn sums on load).
// 128 rowblk x 4 coljobs(64) x 2 khalf = 1024 blocks, 12 KB LDS.
// ---------------------------------------------------------------------------
__global__ __launch_bounds__(256, 8) void proj2_kernel(
    const float* __restrict__ A, const float* __restrict__ Wq,
    float* __restrict__ Qa, float* __restrict__ Qb)
{
    __shared__ float xt[KC * 32];   // 4 KB
    __shared__ float wt[KC * 64];   // 8 KB

    const int t  = threadIdx.x;
    const int kh = blockIdx.x & 1;
    const int bj = (blockIdx.x >> 1) & 3;
    const int br = blockIdx.x >> 3;
    const int r0 = br * 32;
    const int c0 = bj * 64;
    const int kb = kh * 256;
    float* dst = kh ? Qb : Qa;

    const int cq = t & 15;          // cols cq*4..+3 (64 cols)
    const int rr = t >> 4;          // rows rr*2..+1
    const int rs = t & 31, kq = t >> 5;

    float4 acc[2];
    acc[0] = make_float4(0.f, 0.f, 0.f, 0.f);
    acc[1] = acc[0];

    for (int kc = 0; kc < 256; kc += KC) {
        const float4 xa = *(const float4*)(A + (long)(r0 + rs) * D_MODEL + kb + kc + kq * 4);
        xt[(kq * 4 + 0) * 32 + rs] = xa.x;
        xt[(kq * 4 + 1) * 32 + rs] = xa.y;
        xt[(kq * 4 + 2) * 32 + rs] = xa.z;
        xt[(kq * 4 + 3) * 32 + rs] = xa.w;
#pragma unroll
        for (int i = 0; i < 2; ++i) {
            const int row = i * 16 + (t >> 4);
            *(float4*)(wt + row * 64 + (t & 15) * 4) =
                *(const float4*)(Wq + (long)(kb + kc + row) * 256 + c0 + (t & 15) * 4);
        }
        __syncthreads();
#pragma unroll 4
        for (int k = 0; k < KC; ++k) {
            const float4 w4 = *(const float4*)(wt + k * 64 + cq * 4);
            const float2 x2 = *(const float2*)(xt + k * 32 + rr * 2);
            acc[0] = fma4(x2.x, w4, acc[0]);
            acc[1] = fma4(x2.y, w4, acc[1]);
        }
        __syncthreads();
    }

    const int b  = r0 >> 9;
    const int sb = (r0 & 511) + rr * 2;
    const int h  = (c0 >> 2) + cq;
#pragma unroll
    for (int r = 0; r < 2; ++r)
        *(float4*)(dst + (((long)b * HEAD + h) * SEQ + sb + r) * 4) = acc[r];
}

// ---------------------------------------------------------------------------
// Attention (r0-proven structure): one block per (b, h, q-half); 256 threads,
// 1 query/thread. Head-major inputs -> contiguous staging loads. Online
// softmax in the LOG2 domain (log2(e)/sqrt(DK) folded into Q; v_exp_f32 is
// natively 2^x, saves one mul per key). Causal quirk preserved: masked
// scores are exactly 0 (t=0 in log2 domain) and participate; their lump =
// 2^(-M) * (count, suffixSumV) via chunk-granular suffix sums.
// ---------------------------------------------------------------------------
__global__ __launch_bounds__(256) void attn_kernel(
    const float* __restrict__ Qa, const float* __restrict__ Qb,
    const float* __restrict__ K2, const float* __restrict__ V2,
    float* __restrict__ O, int causal)
{
    extern __shared__ float smem[];
    float* Kl = smem;                 // SEQ*DK = 2048 floats
    float* Vl = smem + SEQ * DK;      // SEQ*DV = 4096 floats
    float* cs = Vl + SEQ * DV;        // 33*DV  =  264 floats (causal only)

    const int t = threadIdx.x;
    const int bh = blockIdx.x >> 1;   // b*64 + h
    const int qhalf = blockIdx.x & 1;
    const int b = bh >> 6;
    const int h = bh & 63;

    // contiguous slices: K 8 KB, V 16 KB
    const float4* Ks = (const float4*)(K2 + (long)bh * SEQ * DK);
    ((float4*)Kl)[t]       = Ks[t];
    ((float4*)Kl)[t + 256] = Ks[t + 256];
    const float4* Vs = (const float4*)(V2 + (long)bh * SEQ * DV);
#pragma unroll
    for (int i = 0; i < 4; ++i)
        ((float4*)Vl)[t + i * 256] = Vs[t + i * 256];
    __syncthreads();

    if (causal) {
        const int ch = t >> 3, d = t & 7;
        float s16 = 0.f;
#pragma unroll
        for (int i = 0; i < 16; ++i) s16 += Vl[(ch * 16 + i) * 8 + d];
        cs[ch * 8 + d] = s16;
        __syncthreads();
        if (t < 8) {
            cs[256 + t] = 0.f;
            float run = 0.f;
            for (int c2 = 31; c2 >= 0; --c2) {
                run += cs[c2 * 8 + t];
                cs[c2 * 8 + t] = run;
            }
        }
        __syncthreads();
    }

    const int q = qhalf * 256 + t;
    float4 qv = *(const float4*)(Qa + ((long)bh * SEQ + q) * 4);
    if (Qb) {                          // stage-2: sum split-K proj partials
        const float4 qw = *(const float4*)(Qb + ((long)bh * SEQ + q) * 4);
        qv.x += qw.x; qv.y += qw.y; qv.z += qw.z; qv.w += qw.w;
    }
    const float cf = 0.5f * 1.44269504088896340736f;  // 1/sqrt(DK) * log2(e)
    const float q0 = qv.x * cf, q1 = qv.y * cf;
    const float q2 = qv.z * cf, q3 = qv.w * cf;

    const int bound = causal ? q : (SEQ - 1);

    float m = -INFINITY, l = 0.f;
    float a0=0.f,a1=0.f,a2=0.f,a3=0.f,a4=0.f,a5=0.f,a6=0.f,a7=0.f;

    int s0 = 0;
    for (; s0 + 8 <= bound + 1; s0 += 8) {
        float sc[8];
#pragma unroll
        for (int i = 0; i < 8; ++i) {
            const float4 k4 = *(const float4*)(Kl + (s0 + i) * 4);
            sc[i] = fmaf(q0, k4.x, fmaf(q1, k4.y, fmaf(q2, k4.z, q3 * k4.w)));
        }
        float gm = fmaxf(fmaxf(fmaxf(sc[0], sc[1]), fmaxf(sc[2], sc[3])),
                         fmaxf(fmaxf(sc[4], sc[5]), fmaxf(sc[6], sc[7])));
        if (gm > m) {
            float scale = __builtin_amdgcn_exp2f(m - gm);
            l *= scale;
            a0*=scale; a1*=scale; a2*=scale; a3*=scale;
            a4*=scale; a5*=scale; a6*=scale; a7*=scale;
            m = gm;
        }
#pragma unroll
        for (int i = 0; i < 8; ++i) {
            float p = __builtin_amdgcn_exp2f(sc[i] - m);
            l += p;
            const float4 v0 = *(const float4*)(Vl + (s0 + i) * 8);
            const float4 v1 = *(const float4*)(Vl + (s0 + i) * 8 + 4);
            a0 = fmaf(p, v0.x, a0); a1 = fmaf(p, v0.y, a1);
            a2 = fmaf(p, v0.z, a2); a3 = fmaf(p, v0.w, a3);
            a4 = fmaf(p, v1.x, a4); a5 = fmaf(p, v1.y, a5);
            a6 = fmaf(p, v1.z, a6); a7 = fmaf(p, v1.w, a7);
        }
    }
    for (int s = s0; s <= bound; ++s) {
        const float4 k4 = *(const float4*)(Kl + s * 4);
        float sc = fmaf(q0, k4.x, fmaf(q1, k4.y, fmaf(q2, k4.z, q3 * k4.w)));
        if (sc > m) {
            float scale = __builtin_amdgcn_exp2f(m - sc);
            l *= scale;
            a0*=scale; a1*=scale; a2*=scale; a3*=scale;
            a4*=scale; a5*=scale; a6*=scale; a7*=scale;
            m = sc;
        }
        float p = __builtin_amdgcn_exp2f(sc - m);
        l += p;
        const float4 v0 = *(const float4*)(Vl + s * 8);
        const float4 v1 = *(const float4*)(Vl + s * 8 + 4);
        a0 = fmaf(p, v0.x, a0); a1 = fmaf(p, v0.y, a1);
        a2 = fmaf(p, v0.z, a2); a3 = fmaf(p, v0.w, a3);
        a4 = fmaf(p, v1.x, a4); a5 = fmaf(p, v1.y, a5);
        a6 = fmaf(p, v1.z, a6); a7 = fmaf(p, v1.w, a7);
    }

    if (causal && q < SEQ - 1) {
        float M = fmaxf(m, 0.f);               // masked keys contribute t=0
        float scale = __builtin_amdgcn_exp2f(m - M);
        float pm = __builtin_amdgcn_exp2f(-M);
        l = l * scale + pm * (float)(SEQ - 1 - q);
        int nq = q + 1;
        int cq2 = nq >> 4;
        float sv[8];
#pragma unroll
        for (int d = 0; d < 8; ++d) sv[d] = cs[(cq2 + 1) * 8 + d];
        for (int s = nq; s < (cq2 + 1) * 16; ++s) {
            const float4 v0 = *(const float4*)(Vl + s * 8);
            const float4 v1 = *(const float4*)(Vl + s * 8 + 4);
            sv[0]+=v0.x; sv[1]+=v0.y; sv[2]+=v0.z; sv[3]+=v0.w;
            sv[4]+=v1.x; sv[5]+=v1.y; sv[6]+=v1.z; sv[7]+=v1.w;
        }
        a0 = a0*scale + pm*sv[0]; a1 = a1*scale + pm*sv[1];
        a2 = a2*scale + pm*sv[2]; a3 = a3*scale + pm*sv[3];
        a4 = a4*scale + pm*sv[4]; a5 = a5*scale + pm*sv[5];
        a6 = a6*scale + pm*sv[6]; a7 = a7*scale + pm*sv[7];
    }

    float inv = 1.0f / l;
    const long obase = (long)b * SEQ * 512 + (long)q * 512 + h * DV;  // row-major
    *(float4*)(O + obase)     = make_float4(a0*inv, a1*inv, a2*inv, a3*inv);
    *(float4*)(O + obase + 4) = make_float4(a4*inv, a5*inv, a6*inv, a7*inv);
}

// ---------------------------------------------------------------------------
// Fused residual + LayerNorm + MLP (512 -> 10 -> 512), r0-proven.
// One WAVE per row (no __syncthreads); 256 threads = 4 rows/block.
// ---------------------------------------------------------------------------
__global__ __launch_bounds__(256) void ln_mlp_kernel(
    const float* __restrict__ x, const float* __restrict__ fx,
    const float* __restrict__ g, const float* __restrict__ beta,
    const float* __restrict__ w1, const float* __restrict__ b1,
    const float* __restrict__ w2, const float* __restrict__ b2,
    float* __restrict__ out)
{
    const int t = threadIdx.x;
    const int lane = t & 63;
    const int row = blockIdx.x * 4 + (t >> 6);
    const long base = (long)row * D_MODEL;
    const int e0 = lane * 8;

    const float4 xa = *(const float4*)(x + base + e0);
    const float4 xb = *(const float4*)(x + base + e0 + 4);
    const float4 fa = *(const float4*)(fx + base + e0);
    const float4 fb = *(const float4*)(fx + base + e0 + 4);
    float z[8] = {xa.x+fa.x, xa.y+fa.y, xa.z+fa.z, xa.w+fa.w,
                  xb.x+fb.x, xb.y+fb.y, xb.z+fb.z, xb.w+fb.w};

    float sum = 0.f;
#pragma unroll
    for (int j = 0; j < 8; ++j) sum += z[j];
#pragma unroll
    for (int o = 32; o > 0; o >>= 1) sum += __shfl_xor(sum, o);
    float mu = sum * (1.0f / 512.0f);

    float d[8], ss = 0.f;
#pragma unroll
    for (int j = 0; j < 8; ++j) { d[j] = z[j] - mu; ss += d[j] * d[j]; }
#pragma unroll
    for (int o = 32; o > 0; o >>= 1) ss += __shfl_xor(ss, o);
    float rs = rsqrtf(ss * (1.0f / 512.0f) + 1e-5f);

    const float4 ga = *(const float4*)(g + e0);
    const float4 gb = *(const float4*)(g + e0 + 4);
    const float4 ba = *(const float4*)(beta + e0);
    const float4 bb = *(const float4*)(beta + e0 + 4);
    const float gg[8] = {ga.x,ga.y,ga.z,ga.w,gb.x,gb.y,gb.z,gb.w};
    const float bt[8] = {ba.x,ba.y,ba.z,ba.w,bb.x,bb.y,bb.z,bb.w};
    float y[8];
#pragma unroll
    for (int j = 0; j < 8; ++j) y[j] = d[j] * rs * gg[j] + bt[j];

    float part[HIDD];
#pragma unroll
    for (int i = 0; i < HIDD; ++i) {
        const float4 wa = *(const float4*)(w1 + i * 512 + e0);
        const float4 wb = *(const float4*)(w1 + i * 512 + e0 + 4);
        part[i] = y[0]*wa.x + y[1]*wa.y + y[2]*wa.z + y[3]*wa.w
                + y[4]*wb.x + y[5]*wb.y + y[6]*wb.z + y[7]*wb.w;
    }
#pragma unroll
    for (int i = 0; i < HIDD; ++i)
#pragma unroll
        for (int o = 32; o > 0; o >>= 1) part[i] += __shfl_xor(part[i], o);

    float hv[HIDD];
#pragma unroll
    for (int i = 0; i < HIDD; ++i) hv[i] = fmaxf(part[i] + b1[i], 0.f);

    float o8[8];
#pragma unroll
    for (int j = 0; j < 8; ++j) o8[j] = b2[e0 + j];
#pragma unroll
    for (int i = 0; i < HIDD; ++i)
#pragma unroll
        for (int j = 0; j < 8; ++j)
            o8[j] = fmaf(hv[i], w2[(long)(e0 + j) * 10 + i], o8[j]);

    *(float4*)(out + base + e0)     = make_float4(o8[0], o8[1], o8[2], o8[3]);
    *(float4*)(out + base + e0 + 4) = make_float4(o8[4], o8[5], o8[6], o8[7]);
}

extern "C" void kernel_launch(void* const* d_in, const int* in_sizes, int n_in,
                              void* d_out, int out_size, void* d_ws, size_t ws_size,
                              hipStream_t stream) {
    (void)in_sizes; (void)n_in; (void)out_size; (void)ws_size;
    const float* x    = (const float*)d_in[0];
    const float* xenc = (const float*)d_in[1];
    const float* Wq   = (const float*)d_in[2];
    const float* Wk   = (const float*)d_in[3];
    const float* Wv   = (const float*)d_in[4];
    const float* ln_g = (const float*)d_in[5];
    const float* ln_b = (const float*)d_in[6];
    const float* w1   = (const float*)d_in[7];
    const float* b1   = (const float*)d_in[8];
    const float* w2   = (const float*)d_in[9];
    const float* b2   = (const float*)d_in[10];
    float* out = (float*)d_out;

    // Workspace: 11.5M floats = 46 MiB, all regions disjoint (no aliasing).
    float* ws = (float*)d_ws;
    float* Q1 = ws;                    // [ 0M, 1M)  self Q   head-major
    float* K1 = ws +  1048576;         // [ 1M, 2M)  self K
    float* V1 = ws +  2097152;         // [ 2M, 4M)  self V
    float* Kc = ws +  4194304;         // [ 4M, 5M)  cross K (from x_enc)
    float* Vc = ws +  5242880;         // [ 5M, 7M)  cross V
    float* A  = ws +  7340032;         // [ 7M, 9M)  attn out, row-major [b][s][512]
    float* Qa = ws +  9437184;         // [ 9M,10M)  stage-2 Q, k-half 0
    float* Qb = ws + 10485760;         // [10M,11M)  stage-2 Q, k-half 1

    const size_t lds_cross  = (size_t)(SEQ * DK + SEQ * DV) * 4;          // 24576
    const size_t lds_causal = lds_cross + (size_t)(33 * DV) * 4;          // 25632

    // All projections whose inputs exist at t=0 (self QKV + cross KV)
    proj_kernel<<<dim3(896), 256, 0, stream>>>(x, xenc, Wq, Wk, Wv,
                                               Q1, K1, V1, Kc, Vc);
    // Self-attention (causal multiplicative-mask quirk) -> A row-major
    attn_kernel<<<dim3(BATCH * HEAD * 2), 256, lds_causal, stream>>>(
        Q1, nullptr, K1, V1, A, 1);
    // Stage 2: only Q remains (A consumed solely as stage-2 Q)
    proj2_kernel<<<dim3(1024), 256, 0, stream>>>(A, Wq, Qa, Qb);
    // Cross-attention (same weights — faithful quirk) -> A row-major
    attn_kernel<<<dim3(BATCH * HEAD * 2), 256, lds_cross, stream>>>(
        Qa, Qb, Kc, Vc, A, 0);
    // Residual(x) + LayerNorm + MLP
    ln_mlp_kernel<<<dim3(1024), 256, 0, stream>>>(x, A, ln_g, ln_b,
                                                  w1, b1, w2, b2, out);
}